// Round 8
// baseline (724.434 us; speedup 1.0000x reference)
//
#include <hip/hip_runtime.h>

#define TT 128
#define CC 512
#define HIDN 1024
#define HORN 96
#define NB 256
#define NTILE 16     // K tiles of BK=32

typedef _Float16 f16x8 __attribute__((ext_vector_type(8)));
typedef _Float16 f16x4 __attribute__((ext_vector_type(4)));
typedef float f32x16 __attribute__((ext_vector_type(16)));

// Per buffer: X [256 rows][32 k] f32 (32KB, 8-slot XOR-swizzled 128B rows)
//           + W [256 h][hi 64B | lo 64B] f16 (32KB, same swizzle) = 64KB.
// Two buffers = 128KB; the scan overlays the same 128KB per-batch afterwards.
#define XB 0
#define WB 32768
#define BUFSZ 65536
#define SMEM_BYTES 131072

// fp16 two-term split: v = hi + lo, |err| ~ 2^-22 * |v|
__device__ __forceinline__ void cvt_split(const float4 v, f16x4* hi, f16x4* lo) {
    auto h01 = __builtin_amdgcn_cvt_pkrtz(v.x, v.y);
    auto h23 = __builtin_amdgcn_cvt_pkrtz(v.z, v.w);
    auto l01 = __builtin_amdgcn_cvt_pkrtz(v.x - (float)h01.x, v.y - (float)h01.y);
    auto l23 = __builtin_amdgcn_cvt_pkrtz(v.z - (float)h23.x, v.w - (float)h23.y);
    *hi = (f16x4){(_Float16)h01.x, (_Float16)h01.y, (_Float16)h23.x, (_Float16)h23.y};
    *lo = (f16x4){(_Float16)l01.x, (_Float16)l01.y, (_Float16)l23.x, (_Float16)l23.y};
}

__device__ __forceinline__ void cvt_split8(const float4 f0, const float4 f1,
                                           f16x8* hi, f16x8* lo) {
    auto h0 = __builtin_amdgcn_cvt_pkrtz(f0.x, f0.y);
    auto h1 = __builtin_amdgcn_cvt_pkrtz(f0.z, f0.w);
    auto h2 = __builtin_amdgcn_cvt_pkrtz(f1.x, f1.y);
    auto h3 = __builtin_amdgcn_cvt_pkrtz(f1.z, f1.w);
    auto l0 = __builtin_amdgcn_cvt_pkrtz(f0.x - (float)h0.x, f0.y - (float)h0.y);
    auto l1 = __builtin_amdgcn_cvt_pkrtz(f0.z - (float)h1.x, f0.w - (float)h1.y);
    auto l2 = __builtin_amdgcn_cvt_pkrtz(f1.x - (float)h2.x, f1.y - (float)h2.y);
    auto l3 = __builtin_amdgcn_cvt_pkrtz(f1.z - (float)h3.x, f1.w - (float)h3.y);
    *hi = (f16x8){(_Float16)h0.x, (_Float16)h0.y, (_Float16)h1.x, (_Float16)h1.y,
                  (_Float16)h2.x, (_Float16)h2.y, (_Float16)h3.x, (_Float16)h3.y};
    *lo = (f16x8){(_Float16)l0.x, (_Float16)l0.y, (_Float16)l1.x, (_Float16)l1.y,
                  (_Float16)l2.x, (_Float16)l2.y, (_Float16)l3.x, (_Float16)l3.y};
}

__device__ __forceinline__ void gload16(const void* g, void* l) {
    __builtin_amdgcn_global_load_lds(
        (const __attribute__((address_space(1))) unsigned int*)g,
        (__attribute__((address_space(3))) unsigned int*)l, 16, 0, 0);
}

// Prologue: split W1 f32 -> whi/wlo f16 (once), and init out[b,o] = bh[o]
__global__ void __launch_bounds__(256)
snn_cvtw(const float* __restrict__ W1, f16x4* __restrict__ whi, f16x4* __restrict__ wlo,
         const float* __restrict__ bh, float* __restrict__ out)
{
    const int i = blockIdx.x * 256 + threadIdx.x;   // float4 index, 131072 total
    const float4 v = ((const float4*)W1)[i];
    f16x4 hi, lo;
    cvt_split(v, &hi, &lo);
    whi[i] = hi;
    wlo[i] = lo;
    if (i < NB * HORN) out[i] = bh[i % HORN];
}

#define MF(A, B, C) C = __builtin_amdgcn_mfma_f32_32x32x16_f16(A, B, C, 0, 0, 0)

// Fused proj GEMM (split-f16 MFMA, all-gload_lds staging, phase-structured
// pipeline with 1-tile-early load issue) + leaky scan -> memT[b,h]
// grid = 512 (XCD-grouped: 128 b-pairs x 4 h-tiles), block = 512 (8 waves 2x4)
__global__ void __launch_bounds__(512, 2)
snn_proj_scan(const float* __restrict__ x, const _Float16* __restrict__ whi_g,
              const _Float16* __restrict__ wlo_g, const float* __restrict__ b1,
              const float* __restrict__ betap, float* __restrict__ memT)
{
    __shared__ __align__(16) char smem[SMEM_BYTES];

    const int tid  = threadIdx.x;
    const int lane = tid & 63;
    const int wid  = tid >> 6;              // 0..7
    const int wm   = wid >> 2;              // batch half (wave rows = full T of batch wm)
    const int wn   = wid & 3;               // h quarter (64 h)
    const int g2 = lane >> 5, lr = lane & 31;
    const int am = lr & 7;                  // 8-slot swizzle mask (row&7 == lr&7)

    // XCD-bijective: 512 = 8 xcd x 64; consecutive idx share b-pair (4 h-tiles)
    const int lid = blockIdx.x;
    const int idx = lid >> 3;
    const int bp    = (lid & 7) * 16 + (idx >> 2);   // b-pair 0..127
    const int hbase = (idx & 3) * 256;

    // x rows are flat (b*128 + t): this block's 256 rows are contiguous
    const char* xg = (const char*)x + (size_t)bp * 256 * 2048;

    // staging sources (pre-swizzled per-lane global, linear LDS dest — rule #21)
    // chunk = 1KB = 8 rows x 8 slots(16B); lane -> (rr, pp); logical slot uu = pp^rr
    const int rr = lane >> 3, pp = lane & 7;
    const int uu = pp ^ rr;
    // X: wave chunks 4wid+i (i=0..3), rows 32wid+8i+rr, f32 row stride 2048B
    const char* xsrc = xg + (size_t)(32 * wid + rr) * 2048 + uu * 16;
    // W: rows hbase+32wid+8i+rr; logical slot<4 -> hi array else lo; row [hi64|lo64]
    const char* wbs  = (uu < 4) ? (const char*)whi_g : (const char*)wlo_g;
    const char* wsrc = wbs + (size_t)(hbase + 32 * wid + rr) * 1024 + (uu & 3) * 16;

    // fragment row bases (m/n added as literal*4096)
    const int arow = (wm * 128 + lr) * 128;          // X region
    const int brow = WB + (wn * 64 + lr) * 128;      // W region

    f32x16 acc00 = {}, acc01 = {}, acc10 = {}, acc11 = {};
    f32x16 acc20 = {}, acc21 = {}, acc30 = {}, acc31 = {};

#define STAGE(S, BB) { \
        _Pragma("unroll") \
        for (int i = 0; i < 4; ++i) { \
            gload16(xsrc + (size_t)i * (8 * 2048) + (S) * 128, \
                    smem + (BB) + XB + (4 * wid + i) * 1024); \
            gload16(wsrc + (size_t)i * (8 * 1024) + (S) * 64, \
                    smem + (BB) + WB + (4 * wid + i) * 1024); \
        } }

// One phase = one k16-step: frag reads + cvt (+ optional gload issue), then
// barrier-aligned setprio'd MFMA cluster. Per-acc product order hh, hl, lh
// identical to rounds 2-5 -> bit-identical output (absmax regression check).
#define PHASE(CUR, KS, ...) { \
        __VA_ARGS__ \
        const int ub = (((KS) * 2 + g2) ^ am) << 4; \
        const f16x8 bh0 = *(const f16x8*)(smem + (CUR) + brow + 0 * 4096 + ub); \
        const f16x8 bl0 = *(const f16x8*)(smem + (CUR) + brow + 0 * 4096 + (ub ^ 64)); \
        const f16x8 bh1 = *(const f16x8*)(smem + (CUR) + brow + 1 * 4096 + ub); \
        const f16x8 bl1 = *(const f16x8*)(smem + (CUR) + brow + 1 * 4096 + (ub ^ 64)); \
        const int ua = (((KS) * 4 + g2 * 2) ^ am) << 4; \
        f16x8 ah0, al0, ah1, al1, ah2, al2, ah3, al3; \
        { float4 r0 = *(const float4*)(smem + (CUR) + arow + 0 * 4096 + ua); \
          float4 r1 = *(const float4*)(smem + (CUR) + arow + 0 * 4096 + (ua ^ 16)); \
          cvt_split8(r0, r1, &ah0, &al0); } \
        { float4 r0 = *(const float4*)(smem + (CUR) + arow + 1 * 4096 + ua); \
          float4 r1 = *(const float4*)(smem + (CUR) + arow + 1 * 4096 + (ua ^ 16)); \
          cvt_split8(r0, r1, &ah1, &al1); } \
        { float4 r0 = *(const float4*)(smem + (CUR) + arow + 2 * 4096 + ua); \
          float4 r1 = *(const float4*)(smem + (CUR) + arow + 2 * 4096 + (ua ^ 16)); \
          cvt_split8(r0, r1, &ah2, &al2); } \
        { float4 r0 = *(const float4*)(smem + (CUR) + arow + 3 * 4096 + ua); \
          float4 r1 = *(const float4*)(smem + (CUR) + arow + 3 * 4096 + (ua ^ 16)); \
          cvt_split8(r0, r1, &ah3, &al3); } \
        __builtin_amdgcn_s_barrier(); \
        asm volatile("s_waitcnt lgkmcnt(0)" ::: "memory"); \
        __builtin_amdgcn_sched_barrier(0); \
        __builtin_amdgcn_s_setprio(1); \
        MF(ah0, bh0, acc00); MF(ah0, bh1, acc01); \
        MF(ah1, bh0, acc10); MF(ah1, bh1, acc11); \
        MF(ah2, bh0, acc20); MF(ah2, bh1, acc21); \
        MF(ah3, bh0, acc30); MF(ah3, bh1, acc31); \
        MF(ah0, bl0, acc00); MF(ah0, bl1, acc01); \
        MF(ah1, bl0, acc10); MF(ah1, bl1, acc11); \
        MF(ah2, bl0, acc20); MF(ah2, bl1, acc21); \
        MF(ah3, bl0, acc30); MF(ah3, bl1, acc31); \
        MF(al0, bh0, acc00); MF(al0, bh1, acc01); \
        MF(al1, bh0, acc10); MF(al1, bh1, acc11); \
        MF(al2, bh0, acc20); MF(al2, bh1, acc21); \
        MF(al3, bh0, acc30); MF(al3, bh1, acc31); \
        __builtin_amdgcn_s_setprio(0); \
    }

    // prologue: tile 0 into buf0
    STAGE(0, 0)
    asm volatile("s_waitcnt vmcnt(0)" ::: "memory");
    __builtin_amdgcn_s_barrier();

#pragma unroll 2
    for (int s = 0; s < NTILE; ++s) {
        const int cur = (s & 1) ? BUFSZ : 0;
        const int nxt = (s & 1) ? 0 : BUFSZ;
        // phase 0: issue ALL of next tile's loads here -> ~1.5 phases of coverage
        if (s + 1 < NTILE) {
            PHASE(cur, 0, STAGE(s + 1, nxt))
        } else {
            PHASE(cur, 0, )
        }
        __builtin_amdgcn_s_barrier();
        PHASE(cur, 1, )
        // boundary: waits on loads issued at phase-0 start (nothing younger in flight)
        asm volatile("s_waitcnt vmcnt(0)" ::: "memory");
        __builtin_amdgcn_s_barrier();
    }
#undef PHASE
#undef STAGE

    // ---- epilogue + scan, one batch at a time over the 128KB overlay ----
    // scan buffer: [256 h][128 t] f32 rows of 512B, 16B-slot XOR swizzle.
    // C/D: col=lane&31 (h), t_local = (reg&3) + 8*(reg>>2) + 4*g2, t = m*32 + t_local
#define ST_ACC(A, m, n) { \
        const int row = wn * 64 + (n) * 32 + lr; \
        const int sb  = (m) * 8 + g2; \
        const int rs  = row & 31; \
        char* rb = smem + row * 512; \
        *(float4*)(rb + (((sb + 0) ^ rs) * 16)) = make_float4(A[0],  A[1],  A[2],  A[3]);  \
        *(float4*)(rb + (((sb + 2) ^ rs) * 16)) = make_float4(A[4],  A[5],  A[6],  A[7]);  \
        *(float4*)(rb + (((sb + 4) ^ rs) * 16)) = make_float4(A[8],  A[9],  A[10], A[11]); \
        *(float4*)(rb + (((sb + 6) ^ rs) * 16)) = make_float4(A[12], A[13], A[14], A[15]); }

    const float beta_c = fminf(fmaxf(betap[0], 0.0f), 1.0f);

#pragma unroll
    for (int bb = 0; bb < 2; ++bb) {
        if (wm == bb) {
            ST_ACC(acc00, 0, 0) ST_ACC(acc01, 0, 1)
            ST_ACC(acc10, 1, 0) ST_ACC(acc11, 1, 1)
            ST_ACC(acc20, 2, 0) ST_ACC(acc21, 2, 1)
            ST_ACC(acc30, 3, 0) ST_ACC(acc31, 3, 1)
        }
        __syncthreads();
        if (tid < 256) {
            const int hg = hbase + tid;
            const float b1h = b1[hg];
            const char* rb = smem + tid * 512;
            const int rs = tid & 31;
            float mem = 0.0f;
#pragma unroll
            for (int q = 0; q < 32; ++q) {
                const float4 v = *(const float4*)(rb + ((q ^ rs) * 16));
                float reset;
                reset = (mem > 1.0f) ? 1.0f : 0.0f; mem = beta_c * mem + (v.x + b1h) - reset;
                reset = (mem > 1.0f) ? 1.0f : 0.0f; mem = beta_c * mem + (v.y + b1h) - reset;
                reset = (mem > 1.0f) ? 1.0f : 0.0f; mem = beta_c * mem + (v.z + b1h) - reset;
                reset = (mem > 1.0f) ? 1.0f : 0.0f; mem = beta_c * mem + (v.w + b1h) - reset;
            }
            memT[(size_t)(bp * 2 + bb) * HIDN + hg] = mem;
        }
        __syncthreads();
    }
#undef ST_ACC
}

// Head: out[b,o] += memT[b, kc*64 : +64] . Wh[o, same] (bias pre-stored by cvtw)
__global__ void __launch_bounds__(256)
snn_head(const float* __restrict__ memT, const float* __restrict__ Wh,
         float* __restrict__ out)
{
    __shared__ __align__(16) float ms[16][64];
    __shared__ __align__(16) float ws[HORN][64];
    const int tid = threadIdx.x;
    const int kc = blockIdx.x, bg = blockIdx.y;
    const int kof = kc * 64;

    {
        const int row = tid >> 4, c4 = tid & 15;
        *(float4*)&ms[row][c4 * 4] =
            *(const float4*)(memT + (size_t)(bg * 16 + row) * HIDN + kof + c4 * 4);
    }
#pragma unroll
    for (int r = 0; r < 6; ++r) {
        const int q = r * 256 + tid;
        const int row = q >> 4, c4 = q & 15;
        *(float4*)&ws[row][c4 * 4] =
            *(const float4*)(Wh + (size_t)row * HIDN + kof + c4 * 4);
    }
    __syncthreads();

#pragma unroll
    for (int r = 0; r < 6; ++r) {
        const int p = r * 256 + tid;
        const int bb = p / HORN, o = p % HORN;
        const float4* mv = (const float4*)&ms[bb][0];
        const float4* wv = (const float4*)&ws[o][0];
        float a = 0.0f;
#pragma unroll
        for (int q = 0; q < 16; ++q) {
            const float4 w = wv[q];
            const float4 m = mv[q];
            a = fmaf(w.x, m.x, fmaf(w.y, m.y, fmaf(w.z, m.z, fmaf(w.w, m.w, a))));
        }
        atomicAdd(out + (size_t)(bg * 16 + bb) * HORN + o, a);
    }
}

extern "C" void kernel_launch(void* const* d_in, const int* in_sizes, int n_in,
                              void* d_out, int out_size, void* d_ws, size_t ws_size,
                              hipStream_t stream)
{
    (void)in_sizes; (void)n_in; (void)out_size; (void)ws_size;
    const float* x    = (const float*)d_in[0];
    const float* W1   = (const float*)d_in[1];
    const float* b1   = (const float*)d_in[2];
    const float* Wh   = (const float*)d_in[3];
    const float* bh   = (const float*)d_in[4];
    const float* beta = (const float*)d_in[5];

    // ws layout: whi [1 MB] | wlo [1 MB] | memT [1 MB]
    char* ws = (char*)d_ws;
    _Float16* whi  = (_Float16*)(ws);
    _Float16* wlo  = (_Float16*)(ws + (1 << 20));
    float*    memT = (float*)(ws + (2 << 20));
    float*    out  = (float*)d_out;

    snn_cvtw<<<512, 256, 0, stream>>>(W1, (f16x4*)whi, (f16x4*)wlo, bh, out);
    snn_proj_scan<<<512, 512, 0, stream>>>(x, whi, wlo, b1, beta, memT);
    snn_head<<<dim3(16, 16), 256, 0, stream>>>(memT, Wh, out);
}